// Round 1
// baseline (118.570 us; speedup 1.0000x reference)
//
#include <hip/hip_runtime.h>

// SpikeAmplifier: T=128, N=16, C=1, J=8192.
// Per-element (n,c,j) serial recurrence over t:
//   h = y*h + w*y;  x = x_t + h;  v = v + x;
//   s = (v >= 1);  v = s ? 0 : v;  out[t] = s;  y = s
// Pure streaming, memory-bound: 64 MiB in + 64 MiB out. Roofline ~21 us @ 6.3 TB/s.
//
// R4 change vs R3 (float4, 2 waves/CU, block-prefetch sawtooth):
//  - float2 per thread -> 65536 threads = 1024 blocks x 64 = 4 waves/CU
//    (all 4 SIMDs occupied; per-wave serial VALU chain halved).
//  - Rolling software pipeline, prefetch distance U=16: each unrolled step
//    consumes xbuf[u] and immediately re-issues the load for t+U into the
//    same slot. No vmcnt drain at block boundaries, no xnext register copy.
//    Sustained in-flight reads/CU ~32 KiB (vs 0..16 KiB sawtooth).
//  - Explicit pointer increments (no per-step 64-bit mul).
// Per-element arithmetic order unchanged (bit-exact vs reference: y in {0,1}
// makes h = y*h + w*y exact under any FMA contraction).

#define T_STEPS 128
#define J_DIM   8192
#define NCJ     131072            // N*C*J — per-timestep element count (floats)
#define NCJ2    (NCJ / 2)         // per-timestep stride in float2 units (65536)
#define U       16                // rolling prefetch distance (t-steps)

typedef float v2f __attribute__((ext_vector_type(2)));

__global__ __launch_bounds__(64) void SpikeAmplifier_73452530696745_kernel(
    const float* __restrict__ in,    // (T, N, C, J) fp32
    const float* __restrict__ w,     // (J,) fp32
    float* __restrict__ out)         // (T, N, C, J) fp32 spikes
{
    const int idx2 = blockIdx.x * blockDim.x + threadIdx.x;  // 0 .. NCJ2-1
    const int jbase = (idx2 * 2) & (J_DIM - 1);
    const v2f wv = *(const v2f*)&w[jbase];

    const v2f* __restrict__ in2  = (const v2f*)in;
    v2f* __restrict__       out2 = (v2f*)out;

    v2f h = {0.f, 0.f};
    v2f y = {0.f, 0.f};
    v2f v = {0.f, 0.f};

    // Prologue: fill the pipeline with t = 0..U-1.
    v2f xbuf[U];
    {
        const v2f* p = in2 + idx2;
        #pragma unroll
        for (int u = 0; u < U; ++u) {
            xbuf[u] = __builtin_nontemporal_load(p);
            p += NCJ2;
        }
    }

    const v2f* pld = in2 + idx2 + (size_t)U * NCJ2;  // next load target (t+U)
    v2f*       pst = out2 + idx2;                    // store target (t)

    constexpr int NBLK = T_STEPS / U;   // 8

    // Main loop: T-U steps, each step consumes xbuf[u] and refills it with t+U.
    for (int blk = 0; blk < NBLK - 1; ++blk) {
        #pragma unroll
        for (int u = 0; u < U; ++u) {
            const v2f xt = xbuf[u];
            xbuf[u] = __builtin_nontemporal_load(pld);   // prefetch t+U
            pld += NCJ2;

            v2f yv;
            #pragma unroll
            for (int e = 0; e < 2; ++e) {
                h[e] = y[e] * h[e] + wv[e] * y[e];
                const float x = xt[e] + h[e];
                v[e] = v[e] + x;
                const bool s = (v[e] >= 1.0f);
                y[e] = s ? 1.0f : 0.0f;
                v[e] = s ? 0.0f : v[e];
                yv[e] = y[e];
            }
            __builtin_nontemporal_store(yv, pst);
            pst += NCJ2;
        }
    }

    // Epilogue: last U steps, no prefetch.
    #pragma unroll
    for (int u = 0; u < U; ++u) {
        const v2f xt = xbuf[u];
        v2f yv;
        #pragma unroll
        for (int e = 0; e < 2; ++e) {
            h[e] = y[e] * h[e] + wv[e] * y[e];
            const float x = xt[e] + h[e];
            v[e] = v[e] + x;
            const bool s = (v[e] >= 1.0f);
            y[e] = s ? 1.0f : 0.0f;
            v[e] = s ? 0.0f : v[e];
            yv[e] = y[e];
        }
        __builtin_nontemporal_store(yv, pst);
        pst += NCJ2;
    }
}

extern "C" void kernel_launch(void* const* d_in, const int* in_sizes, int n_in,
                              void* d_out, int out_size, void* d_ws, size_t ws_size,
                              hipStream_t stream) {
    const float* in  = (const float*)d_in[0];   // (T,N,C,J) = 16,777,216 floats
    const float* w   = (const float*)d_in[1];   // (J,) = 8192 floats
    float*       out = (float*)d_out;           // (T,N,C,J)

    // 65536 threads = 1024 blocks x 64 = 4 single-wave blocks per CU.
    SpikeAmplifier_73452530696745_kernel<<<NCJ2 / 64, 64, 0, stream>>>(in, w, out);
}

// Round 2
// 111.906 us; speedup vs baseline: 1.0595x; 1.0595x over previous
//
#include <hip/hip_runtime.h>

// SpikeAmplifier: T=128, N=16, C=1, J=8192.
// Per-element (n,c,j) serial recurrence over t:
//   h = y*h + w*y;  x = x_t + h;  v = v + x;
//   s = (v >= 1);  v = s ? 0 : v;  out[t] = s;  y = s
// Pure streaming, memory-bound: 64 MiB in + 64 MiB out. Kernel roofline ~21 us
// @ 6.3 TB/s; observed kernel portion stuck at ~36 us (~3.7 TB/s) across two
// different software-pipeline structures -> designed load depth (16) is not
// materializing (~1.3 loads/wave in flight by Little's law).
//
// R5 changes vs R4 (float2 rolling pipeline, nt loads+stores, blk back-edge):
//  - NO nontemporal hints. vmcnt decrements in issue order; nt stores ack at
//    HBM-write latency and sit at the queue head, gating every subsequent
//    load-wait. Plain stores ack at L2 (the 6.5 TB/s fills / 6.29 TB/s m13
//    copy both use plain ops).
//  - FULL unroll of the t-loop: straight-line 128 steps, no back-edge, so the
//    waitcnt pass tracks exact outstanding counts and emits precise counted
//    vmcnt(N) waits for the 16-deep rolling buffer instead of conservative
//    loop-header drains. All addresses become compile-time offsets.
//  - Same float2 / 1024x64 grid (4 waves/CU), same rolling depth U=16
//    (bounds live loads -> ~32 VGPR for xbuf, no spill risk).
// Per-element arithmetic order unchanged (bit-exact: y in {0,1} makes
// h = y*h + w*y exact under any FMA contraction).

#define T_STEPS 128
#define J_DIM   8192
#define NCJ     131072            // N*C*J — per-timestep element count (floats)
#define NCJ2    (NCJ / 2)         // per-timestep stride in float2 units (65536)
#define U       16                // rolling prefetch distance (t-steps)

typedef float v2f __attribute__((ext_vector_type(2)));

__global__ __launch_bounds__(64) void SpikeAmplifier_73452530696745_kernel(
    const float* __restrict__ in,    // (T, N, C, J) fp32
    const float* __restrict__ w,     // (J,) fp32
    float* __restrict__ out)         // (T, N, C, J) fp32 spikes
{
    const int idx2 = blockIdx.x * blockDim.x + threadIdx.x;  // 0 .. NCJ2-1
    const int jbase = (idx2 * 2) & (J_DIM - 1);
    const v2f wv = *(const v2f*)&w[jbase];

    const v2f* __restrict__ in2  = (const v2f*)in + idx2;
    v2f* __restrict__       out2 = (v2f*)out + idx2;

    v2f h = {0.f, 0.f};
    v2f y = {0.f, 0.f};
    v2f v = {0.f, 0.f};

    // Fill the 16-deep rolling buffer with t = 0..U-1.
    v2f xbuf[U];
    #pragma unroll
    for (int u = 0; u < U; ++u)
        xbuf[u] = in2[(size_t)u * NCJ2];

    // Straight-line main body: every index is a compile-time constant after
    // unrolling; each step consumes slot (t mod U) and refills it with t+U.
    #pragma unroll
    for (int t = 0; t < T_STEPS; ++t) {
        const v2f xt = xbuf[t & (U - 1)];
        if (t + U < T_STEPS)                       // constant-folds per step
            xbuf[t & (U - 1)] = in2[(size_t)(t + U) * NCJ2];

        v2f yv;
        #pragma unroll
        for (int e = 0; e < 2; ++e) {
            h[e] = y[e] * h[e] + wv[e] * y[e];
            const float x = xt[e] + h[e];
            v[e] = v[e] + x;
            const bool s = (v[e] >= 1.0f);
            y[e] = s ? 1.0f : 0.0f;
            v[e] = s ? 0.0f : v[e];
            yv[e] = y[e];
        }
        out2[(size_t)t * NCJ2] = yv;
    }
}

extern "C" void kernel_launch(void* const* d_in, const int* in_sizes, int n_in,
                              void* d_out, int out_size, void* d_ws, size_t ws_size,
                              hipStream_t stream) {
    const float* in  = (const float*)d_in[0];   // (T,N,C,J) = 16,777,216 floats
    const float* w   = (const float*)d_in[1];   // (J,) = 8192 floats
    float*       out = (float*)d_out;           // (T,N,C,J)

    // 65536 threads = 1024 blocks x 64 = 4 single-wave blocks per CU.
    SpikeAmplifier_73452530696745_kernel<<<NCJ2 / 64, 64, 0, stream>>>(in, w, out);
}